// Round 11
// baseline (242.482 us; speedup 1.0000x reference)
//
#include <hip/hip_runtime.h>
#include <math.h>

#define Bb 2
#define Nn 2048
#define Dd 1024
#define Hh 16
#define HD 64
// M = B*N = 4096 rows

typedef __attribute__((ext_vector_type(8))) short short8;    // 8 bf16 = 4 VGPR (MFMA A/B frag)
typedef __attribute__((ext_vector_type(4))) short short4v;   // 4 bf16 = 2 VGPR (K=16 MFMA frag)
typedef __attribute__((ext_vector_type(4))) float floatx4;   // MFMA C/D frag

// float -> bf16 bits, round-to-nearest-even (values are finite here)
__device__ __forceinline__ short f2bf(float x) {
    unsigned u = __float_as_uint(x);
    u += 0x7fffu + ((u >> 16) & 1u);
    return (short)(u >> 16);
}

// K=16 bf16 MFMA: A-frag layout A[m=lane&15][k=quad*4+j] == C/D layout of the
// S-MFMA -> P feeds PV directly from accumulator registers (no LDS roundtrip).
#if defined(__has_builtin)
#  if __has_builtin(__builtin_amdgcn_mfma_f32_16x16x16bf16_1k)
#    define MFMA16(a, b, c) __builtin_amdgcn_mfma_f32_16x16x16bf16_1k(a, b, c, 0, 0, 0)
#  endif
#endif
#ifndef MFMA16
static __device__ __forceinline__ floatx4 mfma16_asm(short4v a, short4v b, floatx4 c) {
    asm volatile("v_mfma_f32_16x16x16_bf16 %0, %1, %2, %0" : "+v"(c) : "v"(a), "v"(b));
    return c;
}
#  define MFMA16(a, b, c) mfma16_asm(a, b, c)
#endif

// async 16B global -> LDS (DMA; LDS dest is wave-uniform base + lane*16)
__device__ __forceinline__ void gload16(const void* g, void* l) {
    __builtin_amdgcn_global_load_lds(
        (const __attribute__((address_space(1))) unsigned int*)g,
        (__attribute__((address_space(3))) unsigned int*)l,
        16, 0, 0);
}

#define QSCALE 0.18033688011112042f   // 0.125 * log2(e), pre-applied to Q

// ---------------------------------------------------------------------------
// One-shot bf16 cast of x and the four weight matrices.
// ---------------------------------------------------------------------------
__global__ __launch_bounds__(256) void cast_all(
    const float* __restrict__ x,
    const float* __restrict__ Wq, const float* __restrict__ Wk,
    const float* __restrict__ Wv, const float* __restrict__ Wp,
    short* __restrict__ xh, short* __restrict__ Wqh, short* __restrict__ Wkh,
    short* __restrict__ Wvh, short* __restrict__ Wph)
{
    const float* src; short* dst; int n4;
    switch (blockIdx.y) {
        case 0:  src = x;  dst = xh;  n4 = (Bb * Nn * Dd) / 4; break;
        case 1:  src = Wq; dst = Wqh; n4 = (Dd * Dd) / 4; break;
        case 2:  src = Wk; dst = Wkh; n4 = (Dd * Dd) / 4; break;
        case 3:  src = Wv; dst = Wvh; n4 = (Dd * Dd) / 4; break;
        default: src = Wp; dst = Wph; n4 = (Dd * Dd) / 4; break;
    }
    const int i = blockIdx.x * 256 + threadIdx.x;
    if (i >= n4) return;
    float4 v = ((const float4*)src)[i];
    short4v o;
    o.x = f2bf(v.x); o.y = f2bf(v.y); o.z = f2bf(v.z); o.w = f2bf(v.w);
    ((short4v*)dst)[i] = o;
}

// ---------------------------------------------------------------------------
// Fused QKV GEMM with per-head LayerNorm epilogue. Q output additionally
// pre-scaled by QSCALE (Q only feeds flash's exp2). Unchanged from R10.
// ---------------------------------------------------------------------------
__global__ __launch_bounds__(256) void qkv_ln_gemm(
    const short* __restrict__ xh,
    const short* __restrict__ Wqh, const short* __restrict__ Wkh,
    const short* __restrict__ Wvh,
    const float* __restrict__ bq, const float* __restrict__ bk,
    const float* __restrict__ bv,
    const float* __restrict__ qg, const float* __restrict__ qb,
    const float* __restrict__ kg, const float* __restrict__ kb,
    short* __restrict__ Qh, short* __restrict__ Kh, short* __restrict__ Vt)
{
    const int z = blockIdx.z;
    const short* A; const short* W;
    int rowBase, colBase, Nc;
    if (z < 2) { A = xh;  W = z ? Wkh : Wqh;
                 rowBase = blockIdx.x * 128; colBase = blockIdx.y * 128; Nc = Dd; }
    else       { A = Wvh; W = xh;
                 rowBase = blockIdx.y * 128; colBase = blockIdx.x * 128; Nc = Bb * Nn; }

    __shared__ __align__(16) short As[128 * 32];
    __shared__ __align__(16) short Ws[128 * 32];

    const int t    = threadIdx.x;
    const int w    = t >> 6;
    const int lane = t & 63;
    const int quad = lane >> 4;
    const int l15  = lane & 15;
    const int wy   = w >> 1;
    const int wx   = w & 1;

    const int r0 = t >> 2;
    const int kg4 = (t & 3) * 8;
    const short* aP = A + (size_t)(rowBase + r0) * Dd + kg4;
    const short* wP = W + (size_t)(colBase + r0) * Dd + kg4;
    const size_t rowskip = (size_t)64 * Dd;

    floatx4 acc[4][4];
    #pragma unroll
    for (int mi = 0; mi < 4; ++mi)
        #pragma unroll
        for (int ni = 0; ni < 4; ++ni)
            acc[mi][ni] = (floatx4){0.f, 0.f, 0.f, 0.f};

    for (int k0 = 0; k0 < Dd; k0 += 32) {
        gload16(aP,           &As[t * 8]);
        gload16(aP + rowskip, &As[(t + 256) * 8]);
        gload16(wP,           &Ws[t * 8]);
        gload16(wP + rowskip, &Ws[(t + 256) * 8]);
        aP += 32; wP += 32;
        __syncthreads();   // drains vmcnt -> staged tiles visible

        short8 af[4], bfr[4];
        #pragma unroll
        for (int i = 0; i < 4; ++i) {
            af[i]  = *(const short8*)&As[(wy * 64 + i * 16 + l15) * 32 + quad * 8];
            bfr[i] = *(const short8*)&Ws[(wx * 64 + i * 16 + l15) * 32 + quad * 8];
        }
        #pragma unroll
        for (int mi = 0; mi < 4; ++mi)
            #pragma unroll
            for (int ni = 0; ni < 4; ++ni)
                acc[mi][ni] = __builtin_amdgcn_mfma_f32_16x16x32_bf16(
                    af[mi], bfr[ni], acc[mi][ni], 0, 0, 0);
        __syncthreads();
    }

    if (z == 2) {
        #pragma unroll
        for (int mi = 0; mi < 4; ++mi) {
            #pragma unroll
            for (int r = 0; r < 4; ++r) {
                const size_t row = rowBase + wy * 64 + mi * 16 + quad * 4 + r;
                const float brv = bv[row];
                #pragma unroll
                for (int ni = 0; ni < 4; ++ni) {
                    const int col = colBase + wx * 64 + ni * 16 + l15;
                    Vt[row * (size_t)Nc + col] = f2bf(acc[mi][ni][r] + brv);
                }
            }
        }
    } else {
        const float* bias = z ? bk : bq;
        const float* gam  = z ? kg : qg;
        const float* bet  = z ? kb : qb;
        const float oscale = z ? 1.0f : QSCALE;
        short* out = z ? Kh : Qh;
        float bcol[4], g4[4], be4[4];
        #pragma unroll
        for (int ni = 0; ni < 4; ++ni) {
            const int ch = ni * 16 + l15;
            bcol[ni] = bias[colBase + wx * 64 + ch];
            g4[ni]   = gam[ch];
            be4[ni]  = bet[ch];
        }
        #pragma unroll
        for (int mi = 0; mi < 4; ++mi) {
            #pragma unroll
            for (int r = 0; r < 4; ++r) {
                const size_t row = rowBase + wy * 64 + mi * 16 + quad * 4 + r;
                float v[4], s = 0.f, s2 = 0.f;
                #pragma unroll
                for (int ni = 0; ni < 4; ++ni) {
                    v[ni] = acc[mi][ni][r] + bcol[ni];
                    s += v[ni]; s2 += v[ni] * v[ni];
                }
                #pragma unroll
                for (int d = 1; d < 16; d <<= 1) {
                    s  += __shfl_xor(s,  d, 16);
                    s2 += __shfl_xor(s2, d, 16);
                }
                const float mean = s * (1.0f / 64.0f);
                const float var  = s2 * (1.0f / 64.0f) - mean * mean;   // biased (jnp.var)
                const float rr   = rsqrtf(var + 1e-5f);
                #pragma unroll
                for (int ni = 0; ni < 4; ++ni) {
                    const int col = colBase + wx * 64 + ni * 16 + l15;
                    out[row * (size_t)Dd + col] =
                        f2bf(((v[ni] - mean) * rr * g4[ni] + be4[ni]) * oscale);
                }
            }
        }
    }
}

// ---------------------------------------------------------------------------
// Generic bf16 MFMA GEMM: output projection only (unchanged).
// ---------------------------------------------------------------------------
__global__ __launch_bounds__(256) void gemm_mfma(
    const short* __restrict__ A, const short* __restrict__ W,
    const float* __restrict__ bias, float* __restrict__ Cf,
    int M, int K, int Nc)
{
    __shared__ __align__(16) short As[128 * 32];
    __shared__ __align__(16) short Ws[128 * 32];

    const int t    = threadIdx.x;
    const int w    = t >> 6;
    const int lane = t & 63;
    const int quad = lane >> 4;
    const int l15  = lane & 15;
    const int wy   = w >> 1;
    const int wx   = w & 1;
    const int rowBase = blockIdx.y * 128;
    const int colBase = blockIdx.x * 128;

    const int r0 = t >> 2;
    const int kg4 = (t & 3) * 8;
    const short* aP = A + (size_t)(rowBase + r0) * K + kg4;
    const short* wP = W + (size_t)(colBase + r0) * K + kg4;
    const size_t rowskip = (size_t)64 * K;

    floatx4 acc[4][4];
    #pragma unroll
    for (int mi = 0; mi < 4; ++mi)
        #pragma unroll
        for (int ni = 0; ni < 4; ++ni)
            acc[mi][ni] = (floatx4){0.f, 0.f, 0.f, 0.f};

    for (int k0 = 0; k0 < K; k0 += 32) {
        gload16(aP,           &As[t * 8]);
        gload16(aP + rowskip, &As[(t + 256) * 8]);
        gload16(wP,           &Ws[t * 8]);
        gload16(wP + rowskip, &Ws[(t + 256) * 8]);
        aP += 32; wP += 32;
        __syncthreads();

        short8 af[4], bfr[4];
        #pragma unroll
        for (int i = 0; i < 4; ++i) {
            af[i]  = *(const short8*)&As[(wy * 64 + i * 16 + l15) * 32 + quad * 8];
            bfr[i] = *(const short8*)&Ws[(wx * 64 + i * 16 + l15) * 32 + quad * 8];
        }
        #pragma unroll
        for (int mi = 0; mi < 4; ++mi)
            #pragma unroll
            for (int ni = 0; ni < 4; ++ni)
                acc[mi][ni] = __builtin_amdgcn_mfma_f32_16x16x32_bf16(
                    af[mi], bfr[ni], acc[mi][ni], 0, 0, 0);
        __syncthreads();
    }

    #pragma unroll
    for (int mi = 0; mi < 4; ++mi) {
        #pragma unroll
        for (int r = 0; r < 4; ++r) {
            const size_t row = rowBase + wy * 64 + mi * 16 + quad * 4 + r;
            #pragma unroll
            for (int ni = 0; ni < 4; ++ni) {
                const int col = colBase + wx * 64 + ni * 16 + l15;
                Cf[row * Nc + col] = acc[mi][ni][r] + bias[col];
            }
        }
    }
}

// ---------------------------------------------------------------------------
// Flash attention, bf16 MFMA, static-max softmax. Round 11: occupancy/stall
// restructure. Block = 2 waves (128 thr) x 64 queries, grid (32,16,2) = 1024
// blocks -> 4 independent blocks/CU (vs 2): barrier stalls in one block are
// hidden by the other three. K/V LDS is DOUBLE-BUFFERED (36KB) -> ONE
// __syncthreads per tile (was 2), and the prefetched registers are written
// to the alternate buffer at the END of compute so global loads get the
// whole iteration to land. Per-wave math unchanged from R10 (32 q/wave,
// P in registers, l on the matrix pipe).
// ---------------------------------------------------------------------------
__global__ __launch_bounds__(128, 4) void flash_mfma(
    const short* __restrict__ Qh, const short* __restrict__ Kh,
    const short* __restrict__ Vt, short* __restrict__ ctx)
{
    const int qt = blockIdx.x;   // 64-query tile
    const int h  = blockIdx.y;
    const int b  = blockIdx.z;

    const int t    = threadIdx.x;   // 0..127
    const int w    = t >> 6;        // 0..1
    const int lane = t & 63;
    const int quad = lane >> 4;
    const int l15  = lane & 15;

    __shared__ __align__(16) short Ksh[2][64][72];   // [buf][key][d]
    __shared__ __align__(16) short Vsh[2][64][72];   // [buf][ch][key]

    const size_t bhead = (size_t)b * Nn * Dd + (size_t)h * HD;

    // Q B-frags: 2 query sets of 16 per wave, registers for all k-tiles
    short8 qf[2][2];
    #pragma unroll
    for (int qs = 0; qs < 2; ++qs) {
        const short* qp = Qh + bhead
            + (size_t)(qt * 64 + w * 32 + qs * 16 + l15) * Dd + quad * 8;
        qf[qs][0] = *(const short8*)qp;
        qf[qs][1] = *(const short8*)(qp + 32);
    }

    floatx4 accO[2][4], accL[2];
    #pragma unroll
    for (int qs = 0; qs < 2; ++qs) {
        #pragma unroll
        for (int n = 0; n < 4; ++n) accO[qs][n] = (floatx4){0.f, 0.f, 0.f, 0.f};
        accL[qs] = (floatx4){0.f, 0.f, 0.f, 0.f};
    }
    short4v ones;
    ones[0] = ones[1] = ones[2] = ones[3] = (short)0x3F80;   // bf16 1.0

    // staging: thread t owns rows s3+16i (i=0..3), k-chunk XOR-swizzled
    const int s3  = t >> 3;                   // 0..15
    const int c3  = ((t & 7) + (s3 & 7)) & 7;
    const int skg = c3 * 8;
    const short* kP = Kh + bhead + (size_t)s3 * Dd + skg;
    const short* vP = Vt + (size_t)(h * 64 + s3) * (Bb * Nn) + (size_t)b * Nn + skg;

    // prefetch tile 0 and write to buffer 0
    short8 kr[4], vr[4];
    #pragma unroll
    for (int i = 0; i < 4; ++i) {
        kr[i] = *(const short8*)(kP + (size_t)(16 * i) * Dd);
        vr[i] = *(const short8*)(vP + (size_t)(16 * i) * (Bb * Nn));
    }
    #pragma unroll
    for (int i = 0; i < 4; ++i) {
        *(short8*)&Ksh[0][s3 + 16 * i][skg] = kr[i];
        *(short8*)&Vsh[0][s3 + 16 * i][skg] = vr[i];
    }
    kP += 64 * Dd; vP += 64;

    int cur = 0;
    for (int k0 = 0; k0 < Nn; k0 += 64) {
        __syncthreads();   // buf[cur] fully staged; prior reads of buf[cur^1] done

        // ---- issue next tile's global loads (land during compute) ----
        #pragma unroll
        for (int i = 0; i < 4; ++i) {
            kr[i] = *(const short8*)(kP + (size_t)(16 * i) * Dd);
            vr[i] = *(const short8*)(vP + (size_t)(16 * i) * (Bb * Nn));
        }
        kP += 64 * Dd; vP += 64;   // last iter strays into adjacent ws buffers (valid mem, unused)

        // ---- S^T = K Q^T from Ksh[cur] ----
        floatx4 accS[2][4];
        #pragma unroll
        for (int n = 0; n < 4; ++n) {
            short8 kf0 = *(const short8*)&Ksh[cur][n * 16 + l15][quad * 8];
            short8 kf1 = *(const short8*)&Ksh[cur][n * 16 + l15][32 + quad * 8];
            #pragma unroll
            for (int qs = 0; qs < 2; ++qs) {
                floatx4 zz = (floatx4){0.f, 0.f, 0.f, 0.f};
                zz = __builtin_amdgcn_mfma_f32_16x16x32_bf16(kf0, qf[qs][0], zz, 0, 0, 0);
                zz = __builtin_amdgcn_mfma_f32_16x16x32_bf16(kf1, qf[qs][1], zz, 0, 0, 0);
                accS[qs][n] = zz;
            }
        }

        // ---- softmax: exp2 (Q pre-scaled) -> perm-pack -> l via MFMA ----
        short4v pfrag[2][4];
        #pragma unroll
        for (int qs = 0; qs < 2; ++qs) {
            #pragma unroll
            for (int n = 0; n < 4; ++n) {
                const unsigned u0 = __float_as_uint(exp2f(accS[qs][n][0]));
                const unsigned u1 = __float_as_uint(exp2f(accS[qs][n][1]));
                const unsigned u2 = __float_as_uint(exp2f(accS[qs][n][2]));
                const unsigned u3 = __float_as_uint(exp2f(accS[qs][n][3]));
                union { uint2 u; short4v s; } pk;
                pk.u.x = __builtin_amdgcn_perm(u1, u0, 0x07060302u);  // trunc-bf16 pair
                pk.u.y = __builtin_amdgcn_perm(u3, u2, 0x07060302u);
                pfrag[qs][n] = pk.s;
                accL[qs] = MFMA16(pk.s, ones, accL[qs]);   // l += P·1 (matrix pipe)
            }
        }

        // ---- O += P V from Vsh[cur] ----
        #pragma unroll
        for (int n = 0; n < 4; ++n) {       // key subtile
            #pragma unroll
            for (int c = 0; c < 4; ++c) {   // channel subtile
                const short4v vb =
                    *(const short4v*)&Vsh[cur][c * 16 + l15][n * 16 + quad * 4];
                accO[0][c] = MFMA16(pfrag[0][n], vb, accO[0][c]);
                accO[1][c] = MFMA16(pfrag[1][n], vb, accO[1][c]);
            }
        }

        // ---- write prefetched tile into the alternate buffer ----
        #pragma unroll
        for (int i = 0; i < 4; ++i) {
            *(short8*)&Ksh[cur ^ 1][s3 + 16 * i][skg] = kr[i];
            *(short8*)&Vsh[cur ^ 1][s3 + 16 * i][skg] = vr[i];
        }
        cur ^= 1;
    }

    // ---- epilogue: accL[qs][r] IS this lane's query's l -> normalize ----
    #pragma unroll
    for (int qs = 0; qs < 2; ++qs) {
        #pragma unroll
        for (int r = 0; r < 4; ++r) {
            const float lr = 1.0f / accL[qs][r];
            short* dst = ctx + (size_t)((b * Nn) + qt * 64 + w * 32 + qs * 16
                                        + quad * 4 + r) * Dd + h * HD + l15;
            #pragma unroll
            for (int n = 0; n < 4; ++n) dst[n * 16] = f2bf(accO[qs][n][r] * lr);
        }
    }
}

// ---------------------------------------------------------------------------
extern "C" void kernel_launch(void* const* d_in, const int* in_sizes, int n_in,
                              void* d_out, int out_size, void* d_ws, size_t ws_size,
                              hipStream_t stream) {
    const float* x   = (const float*)d_in[0];
    const float* Wq  = (const float*)d_in[1];
    const float* bq  = (const float*)d_in[2];
    const float* Wk  = (const float*)d_in[3];
    const float* bk  = (const float*)d_in[4];
    const float* Wv  = (const float*)d_in[5];
    const float* bv  = (const float*)d_in[6];
    const float* Wp  = (const float*)d_in[7];
    const float* bp  = (const float*)d_in[8];
    const float* qg  = (const float*)d_in[9];
    const float* qb  = (const float*)d_in[10];
    const float* kg  = (const float*)d_in[11];
    const float* kb  = (const float*)d_in[12];
    float* out = (float*)d_out;

    const size_t S = (size_t)Bb * Nn * Dd;   // 4,194,304 elements
    short* wsb = (short*)d_ws;               // all-bf16 workspace (48 MB)
    short* xh   = wsb;                       // [0,  8MB)
    short* Vt   = wsb + S;                   // [8, 16MB)  V^T [1024][4096]
    short* Kh   = wsb + 2 * S;               // [16,24MB)
    short* Qh   = wsb + 3 * S;               // [24,32MB)
    short* ctxh = wsb + 4 * S;               // [32,40MB)
    short* Wqh  = wsb + 5 * S;               // [40,48MB) 4 weights, 2MB each
    short* Wkh  = Wqh + Dd * Dd;
    short* Wvh  = Wkh + Dd * Dd;
    short* Wph  = Wvh + Dd * Dd;

    const int M = Bb * Nn;                   // 4096

    cast_all<<<dim3(4096, 5), 256, 0, stream>>>(x, Wq, Wk, Wv, Wp,
                                                xh, Wqh, Wkh, Wvh, Wph);

    // fused QKV projections + per-head LN (Q,K; Q pre-scaled) + transposed V
    qkv_ln_gemm<<<dim3(M / 128, Dd / 128, 3), 256, 0, stream>>>(
        xh, Wqh, Wkh, Wvh, bq, bk, bv, qg, qb, kg, kb, Qh, Kh, Vt);

    flash_mfma<<<dim3(Nn / 64, Hh, Bb), 128, 0, stream>>>(Qh, Kh, Vt, ctxh);

    // output projection (bf16 MFMA, fp32 out + bias)
    gemm_mfma<<<dim3(Dd / 128, M / 128, 1), 256, 0, stream>>>(
        ctxh, Wph, bp, out, M, Dd, Dd);
}